// Round 14
// baseline (141.250 us; speedup 1.0000x reference)
//
#include <hip/hip_runtime.h>
#include <hip/hip_bf16.h>

using sh8   = __attribute__((ext_vector_type(8))) short;
using f32x4 = __attribute__((ext_vector_type(4))) float;

#define DEV __device__ __forceinline__

DEV float leaky(float x) { return x >= 0.f ? x : 0.2f * x; }

DEV unsigned short f2bf(float f) {  // round-to-nearest-even f32 -> bf16 bits
  unsigned u = __float_as_uint(f);
  u += 0x7FFF + ((u >> 16) & 1);
  return (unsigned short)(u >> 16);
}
DEV float bf2f(unsigned short b) { return __uint_as_float(((unsigned)b) << 16); }

// ---------------- weight packing (templated: all dims pow2 -> shifts) ----------------
template<int Cout, int Cin>
DEV void pack7_body(const float* __restrict__ w, unsigned short* __restrict__ wp, int blk) {
  constexpr long plane = (long)(Cin >> 5) * Cout * 32;
  int tid = blk * 256 + threadIdx.x;
  if (tid >= Cout * Cin) return;
  int co = tid / Cin, ci = tid - co * Cin;
  const float* src = w + (long)tid * 7;
  unsigned short* dst = wp + ((long)(ci >> 5) * Cout + co) * 32 + (ci & 31);
  #pragma unroll
  for (int k = 0; k < 7; ++k) dst[k * plane] = f2bf(src[k]);
}
template<int Cout, int Cin>
DEV void packph_body(const float* __restrict__ w, unsigned short* __restrict__ wp, int blk) {
  constexpr long plane = (long)(Cin >> 5) * Cout * 32;
  int tid = blk * 256 + threadIdx.x;
  if (tid >= Cout * Cin) return;
  int co = tid / Cin, ci = tid - co * Cin;
  float wk[7];
  #pragma unroll
  for (int k = 0; k < 7; ++k) wk[k] = w[(long)tid * 7 + k];
  unsigned short* dst = wp + ((long)(ci >> 5) * Cout + co) * 32 + (ci & 31);
  #pragma unroll
  for (int p = 0; p < 4; ++p) {
    #pragma unroll
    for (int d = 0; d < 3; ++d) {
      float s = 0.f;
      #pragma unroll
      for (int k = 0; k < 7; ++k) if (((p + k + 1) >> 2) == d) s += wk[k];
      dst[(p * 3 + d) * plane] = f2bf(s);
    }
  }
}

// ---------------- MLP gemm body (rider blocks inside conv launches) ----------------
DEV void gemm_body(int gb, const float* __restrict__ h, const float* __restrict__ w,
                   float* __restrict__ gpart, int sum2) {
  __shared__ float hl[4][128];
  __shared__ float red[8][4][32];
  const int jb = gb & 31, kc = gb >> 5, k0 = kc * 128;
  for (int i = threadIdx.x; i < 512; i += 256) {
    int bb = i >> 7, kk = i & 127;
    float v;
    if (sum2) {
      int base = ((bb << 10) + k0 + kk) << 1;
      v = h[base] + h[base + 1];
    } else {
      v = h[(bb << 10) + k0 + kk];
    }
    hl[bb][kk] = v;
  }
  __syncthreads();
  const int jl = threadIdx.x & 31, kq = threadIdx.x >> 5;
  const int j = jb * 32 + jl;
  float a0 = 0, a1 = 0, a2 = 0, a3 = 0;
  const float* wp = w + (long)(k0 + kq * 16) * 1024 + j;
  #pragma unroll
  for (int k = 0; k < 16; ++k) {
    float wv = wp[(long)k * 1024];
    a0 += hl[0][kq * 16 + k] * wv;
    a1 += hl[1][kq * 16 + k] * wv;
    a2 += hl[2][kq * 16 + k] * wv;
    a3 += hl[3][kq * 16 + k] * wv;
  }
  red[kq][0][jl] = a0; red[kq][1][jl] = a1; red[kq][2][jl] = a2; red[kq][3][jl] = a3;
  __syncthreads();
  if (threadIdx.x < 128) {
    int bb = threadIdx.x >> 5, j2 = threadIdx.x & 31;
    float s = 0;
    #pragma unroll
    for (int q = 0; q < 8; ++q) s += red[q][bb][j2];
    gpart[((long)kc * 4 + bb) * 1024 + jb * 32 + j2] = s;
  }
}

// ---------------- embed v7: float4 linear staging -> LDS(264) -> aligned b128 MFMA ----------------
// blocks [0,512): embed one (b,band) = 128 rows, 2 phases of 64 rows.
// blocks [512,3232): weight packing riders.
__global__ __launch_bounds__(256)
void embed_pack(const float* __restrict__ x, const float* __restrict__ ew,
                const float* __restrict__ eb, unsigned short* __restrict__ encbf,
                float* __restrict__ ctx,
                const float* __restrict__ cw1, const float* __restrict__ cw2,
                const float* __restrict__ cw3, const float* __restrict__ cw4,
                unsigned short* __restrict__ wbuf) {
  if (blockIdx.x >= 512) {
    int blk = blockIdx.x - 512;
    if (blk < 2048)      pack7_body<512, 1024>(cw1, wbuf, blk);
    else if (blk < 2560) packph_body<256, 512>(cw2, wbuf + 3670016, blk - 2048);
    else if (blk < 2688) packph_body<128, 256>(cw3, wbuf + 5242880, blk - 2560);
    else                 packph_body<64, 128>(cw4, wbuf + 5636096, blk - 2688);
    return;
  }
  __shared__ __align__(16) unsigned short W16[257 * 16];   // [p][f], f>=8 zeroed
  __shared__ __align__(16) unsigned short sv[64 * 264];    // 64 rows bf16, stride 264 (16B rows)
  __shared__ float ctxred[4][8];
  const int tid = threadIdx.x;
  const int bid = blockIdx.x;                // 512 groups of 128 rows
  const long rowbase = (long)bid * 128;
  const int b = bid >> 7, band = bid & 127;

  for (int i = tid; i < 257 * 16; i += 256) {
    int p = i >> 4, f = i & 15;
    W16[i] = (f < 8) ? f2bf(ew[p * 8 + f]) : (unsigned short)0;
  }
  // ---- stage phase 0: linear float4 reads (16B aligned), scatter bf16 to LDS ----
  {
    const float4* src = (const float4*)(x + rowbase * 257);
    #pragma unroll
    for (int it = 0; it < 17; ++it) {
      int i4 = tid + it * 256;
      if (i4 < 4112) {
        float4 v = src[i4];
        int idx = i4 * 4;
        int r = idx / 257, c = idx - r * 257;   // magic-mul
        float vv[4] = {v.x, v.y, v.z, v.w};
        #pragma unroll
        for (int j = 0; j < 4; ++j) {
          int cj = c + j, rj = r;
          if (cj >= 257) { cj -= 257; rj++; }
          sv[rj * 264 + cj] = f2bf(vv[j]);
        }
      }
    }
  }
  __syncthreads();

  const int w = tid >> 6, lane = tid & 63;
  const int m = lane & 15, g = lane >> 4;

  sh8 breg[8];
  #pragma unroll
  for (int kk = 0; kk < 8; ++kk) {
    #pragma unroll
    for (int j = 0; j < 8; ++j)
      breg[kk][j] = (short)W16[(kk * 32 + g * 8 + j) * 16 + m];
  }
  const float w256 = bf2f(W16[256 * 16 + m]);
  const float ebf = (m < 8) ? eb[m] : 0.f;

  float ctx_acc = 0.f;
  #pragma unroll
  for (int ph = 0; ph < 2; ++ph) {
    if (ph) {
      __syncthreads();                       // all phase-0 reads done
      const float4* src = (const float4*)(x + (rowbase + 64) * 257);
      #pragma unroll
      for (int it = 0; it < 17; ++it) {
        int i4 = tid + it * 256;
        if (i4 < 4112) {
          float4 v = src[i4];
          int idx = i4 * 4;
          int r = idx / 257, c = idx - r * 257;
          float vv[4] = {v.x, v.y, v.z, v.w};
          #pragma unroll
          for (int j = 0; j < 4; ++j) {
            int cj = c + j, rj = r;
            if (cj >= 257) { cj -= 257; rj++; }
            sv[rj * 264 + cj] = f2bf(vv[j]);
          }
        }
      }
      __syncthreads();
    }
    f32x4 acc = {0.f, 0.f, 0.f, 0.f};
    const unsigned short* bp0 = sv + (w * 16 + m) * 264 + g * 8;   // 16B aligned
    #pragma unroll
    for (int kk = 0; kk < 8; ++kk) {
      sh8 afr = *(const sh8*)(bp0 + kk * 32);
      acc = __builtin_amdgcn_mfma_f32_16x16x32_bf16(afr, breg[kk], acc, 0, 0, 0);
    }
    const int t0 = ph * 64 + w * 16;
    unsigned short pk[4];
    #pragma unroll
    for (int r = 0; r < 4; ++r) {
      float xv = bf2f(sv[(w * 16 + g * 4 + r) * 264 + 256]);
      float e = acc[r] + xv * w256 + ebf;    // m>=8 lanes: exact 0
      pk[r] = f2bf(e);
      ctx_acc += e;
    }
    if (m < 8) {
      long o = ((long)b * 1024 + m * 128 + band) * 128 + t0 + g * 4;
      *(ushort4*)(encbf + o) = make_ushort4(pk[0], pk[1], pk[2], pk[3]);
    }
  }
  ctx_acc += __shfl_xor(ctx_acc, 16);
  ctx_acc += __shfl_xor(ctx_acc, 32);
  if (lane < 8) ctxred[w][lane] = ctx_acc;
  __syncthreads();
  if (tid < 8) {
    float sv2 = ctxred[0][tid] + ctxred[1][tid] + ctxred[2][tid] + ctxred[3][tid];
    ctx[(long)b * 1024 + tid * 128 + band] = sv2;
  }
}

// ---------------- conv stage 1 (UPS=1, 32-t tiles) + gemm rider ----------------
template<int SPLITK>
__global__ __launch_bounds__(256, 2)
void conv1_g(const unsigned short* __restrict__ act,
             const unsigned short* __restrict__ wpack,
             float* __restrict__ outp, int nconv,
             const float* __restrict__ h, const float* __restrict__ wmlp,
             float* __restrict__ gpart, int sum2) {
  if ((int)blockIdx.x >= nconv) { gemm_body(blockIdx.x - nconv, h, wmlp, gpart, sum2); return; }
  constexpr int Cin = 1024, Cout = 512, Tout = 128, Tin = 128, NC = 38;
  constexpr int cpb = Cin / SPLITK;
  constexpr int ncib = cpb >> 5;
  constexpr int nCibTot = Cin >> 5;

  int bid = blockIdx.x;
  const int sk = bid % SPLITK; bid /= SPLITK;
  const int tt = bid & 3;  bid >>= 2;
  const int cot = bid & 7; bid >>= 3;
  const int b = bid;
  const int t0 = tt << 5, co0 = cot << 6;
  const int ci0 = sk * cpb;

  extern __shared__ unsigned short lin[];    // [ncib][NC][40]

  const unsigned short* actb = act + ((long)b * Cin + ci0) * Tin;
  const int u_base = t0 - 3;
  const int total = cpb * NC;
  for (int i = threadIdx.x; i < total; i += 256) {
    int ci = i / NC, ul = i - ci * NC;
    int u = u_base + ul;
    unsigned short v = 0;
    if (u >= 0 && u < Tin) v = actb[(long)ci * Tin + u];
    lin[((ci >> 5) * NC + ul) * 40 + (ci & 31)] = v;
  }
  __syncthreads();

  const int lane = threadIdx.x & 63, w = threadIdx.x >> 6;
  const int m = lane & 15, g = lane >> 4;

  int boff[2][7];
  #pragma unroll
  for (int s = 0; s < 2; ++s)
    #pragma unroll
    for (int k = 0; k < 7; ++k)
      boff[s][k] = (s * 16 + m + k) * 40 + g * 8;

  const long wlane = ((long)(co0 + w * 16 + m) * 4 + g) * 8;

  f32x4 acc[2];
  #pragma unroll
  for (int s = 0; s < 2; ++s) { acc[s][0] = 0.f; acc[s][1] = 0.f; acc[s][2] = 0.f; acc[s][3] = 0.f; }

  for (int cib = 0; cib < ncib; ++cib) {
    const unsigned short* lb = lin + cib * (NC * 40);
    const int cg = (ci0 >> 5) + cib;
    sh8 a[7];
    #pragma unroll
    for (int k = 0; k < 7; ++k)
      a[k] = *(const sh8*)(wpack + (long)(k * nCibTot + cg) * Cout * 32 + wlane);
    #pragma unroll
    for (int k = 0; k < 7; ++k) {
      #pragma unroll
      for (int s = 0; s < 2; ++s) {
        sh8 bfr = *(const sh8*)(lb + boff[s][k]);
        acc[s] = __builtin_amdgcn_mfma_f32_16x16x32_bf16(a[k], bfr, acc[s], 0, 0, 0);
      }
    }
  }

  float* op = outp + (((long)sk * 4 + b) * Cout + (co0 + w * 16 + g * 4)) * (long)Tout + t0 + m;
  #pragma unroll
  for (int r = 0; r < 4; ++r) {
    #pragma unroll
    for (int s = 0; s < 2; ++s)
      op[(long)r * Tout + s * 16] = acc[s][r];
  }
}

// ---------------- phase-decomposed conv (32-u tiles) + fused bn-apply + gemm rider ----------------
template<int SPLITK>
__global__ __launch_bounds__(256, 2)
void conv_ph_g(const float* __restrict__ csum_in, const float* __restrict__ sp,
               const float* __restrict__ g, const float* __restrict__ be,
               const unsigned short* __restrict__ wpack,
               float* __restrict__ outp,
               int Cin, int Cout, int Tin, int nconv,
               const float* __restrict__ h, const float* __restrict__ wmlp,
               float* __restrict__ gpart, int sum2) {
  if ((int)blockIdx.x >= nconv) { gemm_body(blockIdx.x - nconv, h, wmlp, gpart, sum2); return; }
  constexpr int NC = 34;
  const int Tout = Tin << 2;
  const int cpb = Cin / SPLITK;
  const int ncib = cpb >> 5;
  const int nCibTot = Cin >> 5;
  const int nco = Cout >> 6, ntu = Tin >> 5;

  int bid = blockIdx.x;
  const int sk = bid % SPLITK; bid /= SPLITK;
  const int tu = bid % ntu; bid /= ntu;
  const int cot = bid % nco; bid /= nco;
  const int b = bid;
  const int u0 = tu << 5, co0 = cot << 6;
  const int ci0 = sk * cpb;

  extern __shared__ unsigned short lin[];    // [ncib][NC][40]
  __shared__ float ssc[128], ssh[128];

  if (threadIdx.x < cpb) {
    int c = ci0 + threadIdx.x;
    float S = sp[c * 4] + sp[c * 4 + 1] + sp[c * 4 + 2] + sp[c * 4 + 3];
    float Q = sp[Cin * 4 + c * 4] + sp[Cin * 4 + c * 4 + 1] + sp[Cin * 4 + c * 4 + 2] + sp[Cin * 4 + c * 4 + 3];
    float n = 4.f * (float)Tin;
    float mean = S / n;
    float var = Q / n - mean * mean;
    float sc = g[c] * rsqrtf(var + 1e-5f);
    ssc[threadIdx.x] = sc;
    ssh[threadIdx.x] = be[c] - mean * sc;
  }
  __syncthreads();

  const float* csb = csum_in + ((long)b * Cin + ci0) * Tin;
  const int total = cpb * NC;
  for (int i = threadIdx.x; i < total; i += 256) {
    int ci = i / NC, r = i - ci * NC;
    int u = u0 - 1 + r;
    unsigned short v = 0;
    if (u >= 0 && u < Tin) {
      float t = csb[(long)ci * Tin + u];
      v = f2bf(leaky(t * ssc[ci] + ssh[ci]));
    }
    lin[((ci >> 5) * NC + r) * 40 + (ci & 31)] = v;
  }
  __syncthreads();

  const int lane = threadIdx.x & 63, w = threadIdx.x >> 6;
  const int m = lane & 15, g2 = lane >> 4;

  int boff[2][3];
  #pragma unroll
  for (int s = 0; s < 2; ++s)
    #pragma unroll
    for (int d = 0; d < 3; ++d)
      boff[s][d] = (s * 16 + m + d) * 40 + g2 * 8;

  const long wlane = ((long)(co0 + w * 16 + m)) * 32 + g2 * 8;

  f32x4 acc[2][4];                           // [s][p]
  #pragma unroll
  for (int s = 0; s < 2; ++s)
    #pragma unroll
    for (int p = 0; p < 4; ++p) { acc[s][p][0] = 0.f; acc[s][p][1] = 0.f; acc[s][p][2] = 0.f; acc[s][p][3] = 0.f; }

  for (int cib = 0; cib < ncib; ++cib) {
    const unsigned short* lb = lin + cib * (NC * 40);
    const int cg = (ci0 >> 5) + cib;
    sh8 a[12];
    #pragma unroll
    for (int pd = 0; pd < 12; ++pd)
      a[pd] = *(const sh8*)(wpack + ((long)(pd * nCibTot + cg) * Cout) * 32 + wlane);
    #pragma unroll
    for (int s = 0; s < 2; ++s) {
      sh8 b0 = *(const sh8*)(lb + boff[s][0]);
      sh8 b1 = *(const sh8*)(lb + boff[s][1]);
      sh8 b2 = *(const sh8*)(lb + boff[s][2]);
      acc[s][0] = __builtin_amdgcn_mfma_f32_16x16x32_bf16(a[0],  b0, acc[s][0], 0, 0, 0);
      acc[s][0] = __builtin_amdgcn_mfma_f32_16x16x32_bf16(a[1],  b1, acc[s][0], 0, 0, 0);
      acc[s][1] = __builtin_amdgcn_mfma_f32_16x16x32_bf16(a[3],  b0, acc[s][1], 0, 0, 0);
      acc[s][1] = __builtin_amdgcn_mfma_f32_16x16x32_bf16(a[4],  b1, acc[s][1], 0, 0, 0);
      acc[s][1] = __builtin_amdgcn_mfma_f32_16x16x32_bf16(a[5],  b2, acc[s][1], 0, 0, 0);
      acc[s][2] = __builtin_amdgcn_mfma_f32_16x16x32_bf16(a[6],  b0, acc[s][2], 0, 0, 0);
      acc[s][2] = __builtin_amdgcn_mfma_f32_16x16x32_bf16(a[7],  b1, acc[s][2], 0, 0, 0);
      acc[s][2] = __builtin_amdgcn_mfma_f32_16x16x32_bf16(a[8],  b2, acc[s][2], 0, 0, 0);
      acc[s][3] = __builtin_amdgcn_mfma_f32_16x16x32_bf16(a[10], b1, acc[s][3], 0, 0, 0);
      acc[s][3] = __builtin_amdgcn_mfma_f32_16x16x32_bf16(a[11], b2, acc[s][3], 0, 0, 0);
    }
  }

  float* op = outp + (((long)sk * 4 + b) * Cout + (co0 + w * 16 + g2 * 4)) * (long)Tout;
  #pragma unroll
  for (int r = 0; r < 4; ++r) {
    #pragma unroll
    for (int s = 0; s < 2; ++s) {
      float4 v4 = make_float4(acc[s][0][r], acc[s][1][r], acc[s][2][r], acc[s][3][r]);
      *(float4*)(op + (long)r * Tout + ((u0 + s * 16 + m) << 2)) = v4;
    }
  }
}

// ---------------- bn stats (1D grid) + lnsum / fin riders ----------------
__global__ __launch_bounds__(256)
void bnsum_ln(const float* __restrict__ p, float* __restrict__ sp,
              float* __restrict__ csum, int C, int T, int SK, int docopy, int mode,
              const float* __restrict__ gpart, const float* __restrict__ bias,
              const float* __restrict__ g, const float* __restrict__ be,
              float* __restrict__ outp) {
  const int nbn = C * 4;
  if ((int)blockIdx.x >= nbn) {
    if (mode == 1) {
      int b = blockIdx.x - nbn;
      __shared__ float buf[1024];
      __shared__ float rs2[4], rq2[4];
      float s = 0, q = 0;
      #pragma unroll
      for (int i = 0; i < 4; ++i) {
        int j = threadIdx.x + i * 256;
        float v = bias[j];
        #pragma unroll
        for (int kc = 0; kc < 8; ++kc) v += gpart[((long)kc * 4 + b) * 1024 + j];
        v = leaky(v);
        buf[j] = v; s += v; q += v * v;
      }
      #pragma unroll
      for (int off = 32; off; off >>= 1) { s += __shfl_down(s, off); q += __shfl_down(q, off); }
      int wid = threadIdx.x >> 6, lane = threadIdx.x & 63;
      if (lane == 0) { rs2[wid] = s; rq2[wid] = q; }
      __syncthreads();
      float S = rs2[0] + rs2[1] + rs2[2] + rs2[3];
      float Q = rq2[0] + rq2[1] + rq2[2] + rq2[3];
      float mean = S * (1.f / 1024.f);
      float var = Q * (1.f / 1024.f) - mean * mean;
      float rstd = rsqrtf(var + 1e-5f);
      #pragma unroll
      for (int i = 0; i < 4; ++i) {
        int j = threadIdx.x + i * 256;
        outp[b * 1024 + j] = (buf[j] - mean) * rstd * g[j] + be[j];
      }
    } else {
      int i = (blockIdx.x - nbn) * 256 + threadIdx.x;
      int b = i >> 10, j = i & 1023;
      float v = bias[j];
      #pragma unroll
      for (int kc = 0; kc < 8; ++kc) v += gpart[((long)kc * 4 + b) * 1024 + j];
      outp[i] = v;
    }
    return;
  }
  const int c = blockIdx.x >> 2, b = blockIdx.x & 3;
  long stride = (long)4 * C * T;
  const float* r = p + ((long)b * C + c) * T;
  float* cw = csum + ((long)b * C + c) * T;
  float s = 0, q = 0;
  for (int t = threadIdx.x; t < T; t += 256) {
    float v = r[t];
    for (int k = 1; k < SK; ++k) v += r[t + k * stride];
    if (docopy) cw[t] = v;
    s += v; q += v * v;
  }
  #pragma unroll
  for (int off = 32; off; off >>= 1) { s += __shfl_down(s, off); q += __shfl_down(q, off); }
  __shared__ float rs[4], rq[4];
  int wid = threadIdx.x >> 6, lane = threadIdx.x & 63;
  if (lane == 0) { rs[wid] = s; rq[wid] = q; }
  __syncthreads();
  if (threadIdx.x == 0) {
    sp[c * 4 + b] = rs[0] + rs[1] + rs[2] + rs[3];
    sp[C * 4 + c * 4 + b] = rq[0] + rq[1] + rq[2] + rq[3];
  }
}

// ---------------- final conv: phase-decomposed 3-tap, FUSED bn-apply staging ----------------
__global__ __launch_bounds__(256)
void conv5_kernel(const float* __restrict__ csum_in, const float* __restrict__ sp,
                  const float* __restrict__ g, const float* __restrict__ be,
                  const float* __restrict__ wgt, const float* __restrict__ bias,
                  float* __restrict__ out, int Tout) {
  __shared__ unsigned short sv[64 * 66];
  __shared__ float wph[64 * 13];
  __shared__ float ssc[64], ssh[64];

  const int b = blockIdx.y;
  const int u0 = blockIdx.x * 64;
  const int Tin = Tout >> 2;
  const int tid = threadIdx.x;

  {
    int ci = tid >> 2, pp = tid & 3;
    float s0 = 0, s1 = 0, s2 = 0;
    #pragma unroll
    for (int k = 0; k < 7; ++k) {
      int d = (pp - 3 + k + 4) >> 2;
      float wv = wgt[ci * 7 + k];
      if (d == 0) s0 += wv; else if (d == 1) s1 += wv; else s2 += wv;
    }
    wph[ci * 13 + pp * 3 + 0] = s0;
    wph[ci * 13 + pp * 3 + 1] = s1;
    wph[ci * 13 + pp * 3 + 2] = s2;
  }
  if (tid < 64) {
    float S = sp[tid * 4] + sp[tid * 4 + 1] + sp[tid * 4 + 2] + sp[tid * 4 + 3];
    float Q = sp[256 + tid * 4] + sp[256 + tid * 4 + 1] + sp[256 + tid * 4 + 2] + sp[256 + tid * 4 + 3];
    float n = 4.f * (float)Tin;
    float mean = S / n;
    float var = Q / n - mean * mean;
    float sc = g[tid] * rsqrtf(var + 1e-5f);
    ssc[tid] = sc;
    ssh[tid] = be[tid] - mean * sc;
  }
  __syncthreads();

  const float* inb = csum_in + (long)b * 64 * Tin;
  for (int i = tid; i < 64 * 66; i += 256) {
    int ci = i / 66, uu = i - ci * 66;
    int u = u0 - 1 + uu;
    unsigned short v = 0;
    if (u >= 0 && u < Tin) {
      float t = inb[(long)ci * Tin + u];
      v = f2bf(leaky(t * ssc[ci] + ssh[ci]));
    }
    sv[ci * 66 + uu] = v;
  }
  __syncthreads();

  const int ul = tid >> 2;
  const int chunk = tid & 3;
  float a0 = 0, a1 = 0, a2 = 0, a3 = 0;
  #pragma unroll
  for (int cc = 0; cc < 16; ++cc) {
    int ci = chunk * 16 + cc;
    float v0 = bf2f(sv[ci * 66 + ul]);
    float v1 = bf2f(sv[ci * 66 + ul + 1]);
    float v2 = bf2f(sv[ci * 66 + ul + 2]);
    const float* wp = wph + ci * 13;
    a0 += v0 * wp[0] + v1 * wp[1];
    a1 += v0 * wp[3] + v1 * wp[4] + v2 * wp[5];
    a2 += v0 * wp[6] + v1 * wp[7] + v2 * wp[8];
    a3 += v1 * wp[10] + v2 * wp[11];
  }
  #pragma unroll
  for (int msk = 1; msk <= 2; msk <<= 1) {
    a0 += __shfl_xor(a0, msk);
    a1 += __shfl_xor(a1, msk);
    a2 += __shfl_xor(a2, msk);
    a3 += __shfl_xor(a3, msk);
  }
  if (chunk == 0) {
    float bv = bias[0];
    float4 r = make_float4(a0 + bv, a1 + bv, a2 + bv, a3 + bv);
    *(float4*)(out + (long)b * Tout + (long)(u0 + ul) * 4) = r;
  }
}

extern "C" void kernel_launch(void* const* d_in, const int* in_sizes, int n_in,
                              void* d_out, int out_size, void* d_ws, size_t ws_size,
                              hipStream_t stream) {
  const float* x     = (const float*)d_in[0];
  // d_in[1] = atoms: dead (sparse_code result unused by outputs)
  const float* ew    = (const float*)d_in[2];
  const float* eb    = (const float*)d_in[3];
  const float* w1    = (const float*)d_in[4];
  const float* b1    = (const float*)d_in[5];
  const float* g1    = (const float*)d_in[6];
  const float* be1   = (const float*)d_in[7];
  const float* w2    = (const float*)d_in[8];
  const float* b2    = (const float*)d_in[9];
  const float* g2    = (const float*)d_in[10];
  const float* be2   = (const float*)d_in[11];
  const float* w3    = (const float*)d_in[12];
  const float* b3    = (const float*)d_in[13];
  const float* up_w1 = (const float*)d_in[14];
  const float* up_b1 = (const float*)d_in[15];
  const float* bn_g1 = (const float*)d_in[16];
  const float* bn_b1 = (const float*)d_in[17];
  const float* up_w2 = (const float*)d_in[18];
  const float* up_b2 = (const float*)d_in[19];
  const float* bn_g2 = (const float*)d_in[20];
  const float* bn_b2 = (const float*)d_in[21];
  const float* up_w3 = (const float*)d_in[22];
  const float* up_b3 = (const float*)d_in[23];
  const float* bn_g3 = (const float*)d_in[24];
  const float* bn_b3 = (const float*)d_in[25];
  const float* up_w4 = (const float*)d_in[26];
  const float* up_b4 = (const float*)d_in[27];
  const float* bn_g4 = (const float*)d_in[28];
  const float* bn_b4 = (const float*)d_in[29];
  const float* up_w5 = (const float*)d_in[30];
  const float* up_b5 = (const float*)d_in[31];

  float* out = (float*)d_out;              // [0,131072) = y, [131072,135168) = ctx_out

  float* ws = (float*)d_ws;
  float* ctxb   = ws;                      // 4096
  float* gpart  = ctxb + 4096;             // 32768
  float* t2     = gpart + 32768;           // 4096
  float* statsp = t2 + 4096;               // 4096
  float* csum   = statsp + 4096;           // 2097152
  float* pbuf   = csum + 2097152;          // 4194304
  unsigned short* encbf = (unsigned short*)(pbuf + 4194304);  // 524288 u16
  unsigned short* wbuf  = encbf + 524288;  // 5734400 u16

  // 1: embed v7 (float4 linear staging, aligned b128 MFMA, final ctx) + pack riders
  embed_pack<<<3232, 256, 0, stream>>>(x, ew, eb, encbf, ctxb,
                                       up_w1, up_w2, up_w3, up_w4, wbuf);

  // 2: conv stage 1 (SK=4, 32-t tiles) + MLP gemm1 rider (ctxb -> gpart)
  conv1_g<4><<<768, 256, 24320, stream>>>(encbf, wbuf, pbuf,
                                          512, ctxb, w1, gpart, 0);
  // 3: bnsum1 (SK=4) + lnsum1 rider (gpart -> t2)
  bnsum_ln<<<2052, 256, 0, stream>>>(pbuf, statsp, csum, 512, 128, 4, 1, 1,
                                     gpart, b1, g1, be1, t2);
  // 4: conv stage 2 (SK=4, 32-u tiles) + gemm2 rider (t2 -> gpart)
  conv_ph_g<4><<<512, 256, 10880, stream>>>(csum, statsp, bn_g1, bn_b1, wbuf + 3670016,
                                            pbuf, 512, 256, 128,
                                            256, t2, w2, gpart, 0);
  // 5: bnsum2 (SK=4) + lnsum2 rider (gpart -> t2)
  bnsum_ln<<<1028, 256, 0, stream>>>(pbuf, statsp, csum, 256, 512, 4, 1, 1,
                                     gpart, b2, g2, be2, t2);
  // 6: conv stage 3 (SK=2) + gemm3 rider (t2 -> gpart)
  conv_ph_g<2><<<512, 256, 10880, stream>>>(csum, statsp, bn_g2, bn_b2, wbuf + 5242880,
                                            pbuf, 256, 128, 512,
                                            256, t2, w3, gpart, 0);
  // 7: bnsum3 (SK=2) + fin rider (gpart -> ctx_out)
  bnsum_ln<<<528, 256, 0, stream>>>(pbuf, statsp, csum, 128, 2048, 2, 1, 2,
                                    gpart, b3, b3, b3, out + 131072);
  // 8: conv stage 4 (SK=1 -> writes final sums to pbuf directly)
  conv_ph_g<1><<<256, 256, 10880, stream>>>(csum, statsp, bn_g3, bn_b3, wbuf + 5636096,
                                            pbuf, 128, 64, 2048,
                                            256, t2, w3, gpart, -1);
  // 9: bnsum4 (SK=1, stats only - no copy)
  bnsum_ln<<<256, 256, 0, stream>>>(pbuf, statsp, csum, 64, 8192, 1, 0, 0,
                                    gpart, b3, b3, b3, out + 131072);
  // 10: conv stage 5 (reads pbuf directly)
  conv5_kernel<<<dim3(128, 4), 256, 0, stream>>>(pbuf, statsp, bn_g4, bn_b4, up_w5, up_b5, out, 32768);
}

// Round 15
// 137.941 us; speedup vs baseline: 1.0240x; 1.0240x over previous
//
#include <hip/hip_runtime.h>
#include <hip/hip_bf16.h>

using sh8   = __attribute__((ext_vector_type(8))) short;
using f32x4 = __attribute__((ext_vector_type(4))) float;

#define DEV __device__ __forceinline__

DEV float leaky(float x) { return x >= 0.f ? x : 0.2f * x; }

DEV unsigned short f2bf(float f) {  // round-to-nearest-even f32 -> bf16 bits
  unsigned u = __float_as_uint(f);
  u += 0x7FFF + ((u >> 16) & 1);
  return (unsigned short)(u >> 16);
}
DEV float bf2f(unsigned short b) { return __uint_as_float(((unsigned)b) << 16); }

// ---------------- weight packing (templated: all dims pow2 -> shifts) ----------------
template<int Cout, int Cin>
DEV void pack7_body(const float* __restrict__ w, unsigned short* __restrict__ wp, int blk) {
  constexpr long plane = (long)(Cin >> 5) * Cout * 32;
  int tid = blk * 256 + threadIdx.x;
  if (tid >= Cout * Cin) return;
  int co = tid / Cin, ci = tid - co * Cin;
  const float* src = w + (long)tid * 7;
  unsigned short* dst = wp + ((long)(ci >> 5) * Cout + co) * 32 + (ci & 31);
  #pragma unroll
  for (int k = 0; k < 7; ++k) dst[k * plane] = f2bf(src[k]);
}
template<int Cout, int Cin>
DEV void packph_body(const float* __restrict__ w, unsigned short* __restrict__ wp, int blk) {
  constexpr long plane = (long)(Cin >> 5) * Cout * 32;
  int tid = blk * 256 + threadIdx.x;
  if (tid >= Cout * Cin) return;
  int co = tid / Cin, ci = tid - co * Cin;
  float wk[7];
  #pragma unroll
  for (int k = 0; k < 7; ++k) wk[k] = w[(long)tid * 7 + k];
  unsigned short* dst = wp + ((long)(ci >> 5) * Cout + co) * 32 + (ci & 31);
  #pragma unroll
  for (int p = 0; p < 4; ++p) {
    #pragma unroll
    for (int d = 0; d < 3; ++d) {
      float s = 0.f;
      #pragma unroll
      for (int k = 0; k < 7; ++k) if (((p + k + 1) >> 2) == d) s += wk[k];
      dst[(p * 3 + d) * plane] = f2bf(s);
    }
  }
}

// ---------------- MLP gemm body (rider blocks inside conv launches) ----------------
DEV void gemm_body(int gb, const float* __restrict__ h, const float* __restrict__ w,
                   float* __restrict__ gpart, int sum2) {
  __shared__ float hl[4][128];
  __shared__ float red[8][4][32];
  const int jb = gb & 31, kc = gb >> 5, k0 = kc * 128;
  for (int i = threadIdx.x; i < 512; i += 256) {
    int bb = i >> 7, kk = i & 127;
    float v;
    if (sum2) {
      int base = ((bb << 10) + k0 + kk) << 1;
      v = h[base] + h[base + 1];
    } else {
      v = h[(bb << 10) + k0 + kk];
    }
    hl[bb][kk] = v;
  }
  __syncthreads();
  const int jl = threadIdx.x & 31, kq = threadIdx.x >> 5;
  const int j = jb * 32 + jl;
  float a0 = 0, a1 = 0, a2 = 0, a3 = 0;
  const float* wp = w + (long)(k0 + kq * 16) * 1024 + j;
  #pragma unroll
  for (int k = 0; k < 16; ++k) {
    float wv = wp[(long)k * 1024];
    a0 += hl[0][kq * 16 + k] * wv;
    a1 += hl[1][kq * 16 + k] * wv;
    a2 += hl[2][kq * 16 + k] * wv;
    a3 += hl[3][kq * 16 + k] * wv;
  }
  red[kq][0][jl] = a0; red[kq][1][jl] = a1; red[kq][2][jl] = a2; red[kq][3][jl] = a3;
  __syncthreads();
  if (threadIdx.x < 128) {
    int bb = threadIdx.x >> 5, j2 = threadIdx.x & 31;
    float s = 0;
    #pragma unroll
    for (int q = 0; q < 8; ++q) s += red[q][bb][j2];
    gpart[((long)kc * 4 + bb) * 1024 + jb * 32 + j2] = s;
  }
}

// ---------------- embed (direct-load MFMA) + pack riders ----------------
// blocks [0,1024): embed 64-row groups. blocks [1024,3744): weight packing.
__global__ __launch_bounds__(256)
void embed_pack(const float* __restrict__ x, const float* __restrict__ ew,
                const float* __restrict__ eb, unsigned short* __restrict__ encbf,
                float* __restrict__ part,
                const float* __restrict__ cw1, const float* __restrict__ cw2,
                const float* __restrict__ cw3, const float* __restrict__ cw4,
                unsigned short* __restrict__ wbuf) {
  if (blockIdx.x >= 1024) {
    int blk = blockIdx.x - 1024;
    if (blk < 2048)      pack7_body<512, 1024>(cw1, wbuf, blk);
    else if (blk < 2560) packph_body<256, 512>(cw2, wbuf + 3670016, blk - 2048);
    else if (blk < 2688) packph_body<128, 256>(cw3, wbuf + 5242880, blk - 2560);
    else                 packph_body<64, 128>(cw4, wbuf + 5636096, blk - 2688);
    return;
  }
  __shared__ unsigned short W16[257 * 16];   // [p][f], f>=8 zeroed
  __shared__ float ctxred[4][8];
  const int tid = threadIdx.x;

  for (int i = tid; i < 257 * 16; i += 256) {
    int p = i >> 4, f = i & 15;
    W16[i] = (f < 8) ? f2bf(ew[p * 8 + f]) : (unsigned short)0;
  }
  __syncthreads();

  const int w = tid >> 6, lane = tid & 63;
  const int m = lane & 15, g = lane >> 4;

  sh8 breg[8];
  #pragma unroll
  for (int kk = 0; kk < 8; ++kk) {
    #pragma unroll
    for (int j = 0; j < 8; ++j)
      breg[kk][j] = (short)W16[(kk * 32 + g * 8 + j) * 16 + m];
  }
  const float w256 = bf2f(W16[256 * 16 + m]);
  const float ebf = (m < 8) ? eb[m] : 0.f;

  const int bid = blockIdx.x;
  const long row0 = (long)bid * 64;
  const int b = bid >> 8, band = (bid >> 1) & 127, half = bid & 1;
  const int t0 = half * 64 + w * 16;

  const float* xp = x + (row0 + w * 16 + m) * 257 + g * 8;
  float vals[8][8];
  #pragma unroll
  for (int kk = 0; kk < 8; ++kk) {
    #pragma unroll
    for (int j = 0; j < 8; ++j)
      vals[kk][j] = xp[kk * 32 + j];
  }
  f32x4 acc = {0.f, 0.f, 0.f, 0.f};
  #pragma unroll
  for (int kk = 0; kk < 8; ++kk) {
    sh8 afr;
    #pragma unroll
    for (int j = 0; j < 8; ++j) afr[j] = (short)f2bf(vals[kk][j]);
    acc = __builtin_amdgcn_mfma_f32_16x16x32_bf16(afr, breg[kk], acc, 0, 0, 0);
  }

  const float* xq = x + (row0 + w * 16 + g * 4) * 257 + 256;
  float ctx_acc = 0.f;
  unsigned short pk[4];
  #pragma unroll
  for (int r = 0; r < 4; ++r) {
    float e = acc[r] + xq[(long)r * 257] * w256 + ebf;
    pk[r] = f2bf(e);
    ctx_acc += e;
  }
  if (m < 8) {
    long o = ((long)b * 1024 + m * 128 + band) * 128 + t0 + g * 4;
    *(ushort4*)(encbf + o) = make_ushort4(pk[0], pk[1], pk[2], pk[3]);
  }

  ctx_acc += __shfl_xor(ctx_acc, 16);
  ctx_acc += __shfl_xor(ctx_acc, 32);
  if (lane < 8) ctxred[w][lane] = ctx_acc;
  __syncthreads();
  if (tid < 8) {
    float sv = ctxred[0][tid] + ctxred[1][tid] + ctxred[2][tid] + ctxred[3][tid];
    part[((b * 1024 + tid * 128 + band) << 1) + half] = sv;
  }
}

// ---------------- conv stage 1 (UPS=1, 32-t tiles) + gemm rider ----------------
// Cin=1024, Cout=512, Tout=128 fixed. NC = 32+6 = 38.
template<int SPLITK>
__global__ __launch_bounds__(256, 2)
void conv1_g(const unsigned short* __restrict__ act,
             const unsigned short* __restrict__ wpack,
             float* __restrict__ outp, int nconv,
             const float* __restrict__ h, const float* __restrict__ wmlp,
             float* __restrict__ gpart, int sum2) {
  if ((int)blockIdx.x >= nconv) { gemm_body(blockIdx.x - nconv, h, wmlp, gpart, sum2); return; }
  constexpr int Cin = 1024, Cout = 512, Tout = 128, Tin = 128, NC = 38;
  constexpr int cpb = Cin / SPLITK;
  constexpr int ncib = cpb >> 5;
  constexpr int nCibTot = Cin >> 5;

  int bid = blockIdx.x;
  const int sk = bid % SPLITK; bid /= SPLITK;
  const int tt = bid & 3;  bid >>= 2;        // nt = 4 (32-t tiles)
  const int cot = bid & 7; bid >>= 3;        // nco = 8
  const int b = bid;
  const int t0 = tt << 5, co0 = cot << 6;
  const int ci0 = sk * cpb;

  extern __shared__ unsigned short lin[];    // [ncib][NC][40]

  const unsigned short* actb = act + ((long)b * Cin + ci0) * Tin;
  const int u_base = t0 - 3;
  const int total = cpb * NC;
  for (int i = threadIdx.x; i < total; i += 256) {
    int ci = i / NC, ul = i - ci * NC;
    int u = u_base + ul;
    unsigned short v = 0;
    if (u >= 0 && u < Tin) v = actb[(long)ci * Tin + u];
    lin[((ci >> 5) * NC + ul) * 40 + (ci & 31)] = v;
  }
  __syncthreads();

  const int lane = threadIdx.x & 63, w = threadIdx.x >> 6;
  const int m = lane & 15, g = lane >> 4;

  int boff[2][7];
  #pragma unroll
  for (int s = 0; s < 2; ++s)
    #pragma unroll
    for (int k = 0; k < 7; ++k)
      boff[s][k] = (s * 16 + m + k) * 40 + g * 8;

  const long wlane = ((long)(co0 + w * 16 + m) * 4 + g) * 8;

  f32x4 acc[2];
  #pragma unroll
  for (int s = 0; s < 2; ++s) { acc[s][0] = 0.f; acc[s][1] = 0.f; acc[s][2] = 0.f; acc[s][3] = 0.f; }

  for (int cib = 0; cib < ncib; ++cib) {
    const unsigned short* lb = lin + cib * (NC * 40);
    const int cg = (ci0 >> 5) + cib;
    sh8 a[7];
    #pragma unroll
    for (int k = 0; k < 7; ++k)
      a[k] = *(const sh8*)(wpack + (long)(k * nCibTot + cg) * Cout * 32 + wlane);
    #pragma unroll
    for (int k = 0; k < 7; ++k) {
      #pragma unroll
      for (int s = 0; s < 2; ++s) {
        sh8 bfr = *(const sh8*)(lb + boff[s][k]);
        acc[s] = __builtin_amdgcn_mfma_f32_16x16x32_bf16(a[k], bfr, acc[s], 0, 0, 0);
      }
    }
  }

  float* op = outp + (((long)sk * 4 + b) * Cout + (co0 + w * 16 + g * 4)) * (long)Tout + t0 + m;
  #pragma unroll
  for (int r = 0; r < 4; ++r) {
    #pragma unroll
    for (int s = 0; s < 2; ++s)
      op[(long)r * Tout + s * 16] = acc[s][r];
  }
}

// ---------------- phase-decomposed conv (32-u tiles) + fused bn-apply + gemm rider ----------------
// NC = 32+2 = 34. ssc/ssh sized for cpb<=128.
template<int SPLITK>
__global__ __launch_bounds__(256, 2)
void conv_ph_g(const float* __restrict__ csum_in, const float* __restrict__ sp,
               const float* __restrict__ g, const float* __restrict__ be,
               const unsigned short* __restrict__ wpack,
               float* __restrict__ outp,
               int Cin, int Cout, int Tin, int nconv,
               const float* __restrict__ h, const float* __restrict__ wmlp,
               float* __restrict__ gpart, int sum2) {
  if ((int)blockIdx.x >= nconv) { gemm_body(blockIdx.x - nconv, h, wmlp, gpart, sum2); return; }
  constexpr int NC = 34;
  const int Tout = Tin << 2;
  const int cpb = Cin / SPLITK;
  const int ncib = cpb >> 5;
  const int nCibTot = Cin >> 5;
  const int nco = Cout >> 6, ntu = Tin >> 5;

  int bid = blockIdx.x;
  const int sk = bid % SPLITK; bid /= SPLITK;
  const int tu = bid % ntu; bid /= ntu;
  const int cot = bid % nco; bid /= nco;
  const int b = bid;
  const int u0 = tu << 5, co0 = cot << 6;
  const int ci0 = sk * cpb;

  extern __shared__ unsigned short lin[];    // [ncib][NC][40]
  __shared__ float ssc[128], ssh[128];

  if (threadIdx.x < cpb) {
    int c = ci0 + threadIdx.x;
    float S = sp[c * 4] + sp[c * 4 + 1] + sp[c * 4 + 2] + sp[c * 4 + 3];
    float Q = sp[Cin * 4 + c * 4] + sp[Cin * 4 + c * 4 + 1] + sp[Cin * 4 + c * 4 + 2] + sp[Cin * 4 + c * 4 + 3];
    float n = 4.f * (float)Tin;
    float mean = S / n;
    float var = Q / n - mean * mean;
    float sc = g[c] * rsqrtf(var + 1e-5f);
    ssc[threadIdx.x] = sc;
    ssh[threadIdx.x] = be[c] - mean * sc;
  }
  __syncthreads();

  const float* csb = csum_in + ((long)b * Cin + ci0) * Tin;
  const int total = cpb * NC;
  for (int i = threadIdx.x; i < total; i += 256) {
    int ci = i / NC, r = i - ci * NC;
    int u = u0 - 1 + r;
    unsigned short v = 0;
    if (u >= 0 && u < Tin) {
      float t = csb[(long)ci * Tin + u];
      v = f2bf(leaky(t * ssc[ci] + ssh[ci]));
    }
    lin[((ci >> 5) * NC + r) * 40 + (ci & 31)] = v;
  }
  __syncthreads();

  const int lane = threadIdx.x & 63, w = threadIdx.x >> 6;
  const int m = lane & 15, g2 = lane >> 4;

  int boff[2][3];
  #pragma unroll
  for (int s = 0; s < 2; ++s)
    #pragma unroll
    for (int d = 0; d < 3; ++d)
      boff[s][d] = (s * 16 + m + d) * 40 + g2 * 8;

  const long wlane = ((long)(co0 + w * 16 + m)) * 32 + g2 * 8;

  f32x4 acc[2][4];                           // [s][p]
  #pragma unroll
  for (int s = 0; s < 2; ++s)
    #pragma unroll
    for (int p = 0; p < 4; ++p) { acc[s][p][0] = 0.f; acc[s][p][1] = 0.f; acc[s][p][2] = 0.f; acc[s][p][3] = 0.f; }

  for (int cib = 0; cib < ncib; ++cib) {
    const unsigned short* lb = lin + cib * (NC * 40);
    const int cg = (ci0 >> 5) + cib;
    sh8 a[12];
    #pragma unroll
    for (int pd = 0; pd < 12; ++pd)
      a[pd] = *(const sh8*)(wpack + ((long)(pd * nCibTot + cg) * Cout) * 32 + wlane);
    #pragma unroll
    for (int s = 0; s < 2; ++s) {
      sh8 b0 = *(const sh8*)(lb + boff[s][0]);
      sh8 b1 = *(const sh8*)(lb + boff[s][1]);
      sh8 b2 = *(const sh8*)(lb + boff[s][2]);
      acc[s][0] = __builtin_amdgcn_mfma_f32_16x16x32_bf16(a[0],  b0, acc[s][0], 0, 0, 0);
      acc[s][0] = __builtin_amdgcn_mfma_f32_16x16x32_bf16(a[1],  b1, acc[s][0], 0, 0, 0);
      acc[s][1] = __builtin_amdgcn_mfma_f32_16x16x32_bf16(a[3],  b0, acc[s][1], 0, 0, 0);
      acc[s][1] = __builtin_amdgcn_mfma_f32_16x16x32_bf16(a[4],  b1, acc[s][1], 0, 0, 0);
      acc[s][1] = __builtin_amdgcn_mfma_f32_16x16x32_bf16(a[5],  b2, acc[s][1], 0, 0, 0);
      acc[s][2] = __builtin_amdgcn_mfma_f32_16x16x32_bf16(a[6],  b0, acc[s][2], 0, 0, 0);
      acc[s][2] = __builtin_amdgcn_mfma_f32_16x16x32_bf16(a[7],  b1, acc[s][2], 0, 0, 0);
      acc[s][2] = __builtin_amdgcn_mfma_f32_16x16x32_bf16(a[8],  b2, acc[s][2], 0, 0, 0);
      acc[s][3] = __builtin_amdgcn_mfma_f32_16x16x32_bf16(a[10], b1, acc[s][3], 0, 0, 0);
      acc[s][3] = __builtin_amdgcn_mfma_f32_16x16x32_bf16(a[11], b2, acc[s][3], 0, 0, 0);
    }
  }

  float* op = outp + (((long)sk * 4 + b) * Cout + (co0 + w * 16 + g2 * 4)) * (long)Tout;
  #pragma unroll
  for (int r = 0; r < 4; ++r) {
    #pragma unroll
    for (int s = 0; s < 2; ++s) {
      float4 v4 = make_float4(acc[s][0][r], acc[s][1][r], acc[s][2][r], acc[s][3][r]);
      *(float4*)(op + (long)r * Tout + ((u0 + s * 16 + m) << 2)) = v4;
    }
  }
}

// ---------------- bn stats (1D grid) + lnsum / fin riders ----------------
// blocks [0, C*4): bnsum. mode 1: +4 lnsum blocks. mode 2: +16 fin blocks.
// docopy=0: stats only (no csum write; SK must be 1).
__global__ __launch_bounds__(256)
void bnsum_ln(const float* __restrict__ p, float* __restrict__ sp,
              float* __restrict__ csum, int C, int T, int SK, int docopy, int mode,
              const float* __restrict__ gpart, const float* __restrict__ bias,
              const float* __restrict__ g, const float* __restrict__ be,
              float* __restrict__ outp) {
  const int nbn = C * 4;
  if ((int)blockIdx.x >= nbn) {
    if (mode == 1) {
      int b = blockIdx.x - nbn;
      __shared__ float buf[1024];
      __shared__ float rs2[4], rq2[4];
      float s = 0, q = 0;
      #pragma unroll
      for (int i = 0; i < 4; ++i) {
        int j = threadIdx.x + i * 256;
        float v = bias[j];
        #pragma unroll
        for (int kc = 0; kc < 8; ++kc) v += gpart[((long)kc * 4 + b) * 1024 + j];
        v = leaky(v);
        buf[j] = v; s += v; q += v * v;
      }
      #pragma unroll
      for (int off = 32; off; off >>= 1) { s += __shfl_down(s, off); q += __shfl_down(q, off); }
      int wid = threadIdx.x >> 6, lane = threadIdx.x & 63;
      if (lane == 0) { rs2[wid] = s; rq2[wid] = q; }
      __syncthreads();
      float S = rs2[0] + rs2[1] + rs2[2] + rs2[3];
      float Q = rq2[0] + rq2[1] + rq2[2] + rq2[3];
      float mean = S * (1.f / 1024.f);
      float var = Q * (1.f / 1024.f) - mean * mean;
      float rstd = rsqrtf(var + 1e-5f);
      #pragma unroll
      for (int i = 0; i < 4; ++i) {
        int j = threadIdx.x + i * 256;
        outp[b * 1024 + j] = (buf[j] - mean) * rstd * g[j] + be[j];
      }
    } else {
      int i = (blockIdx.x - nbn) * 256 + threadIdx.x;
      int b = i >> 10, j = i & 1023;
      float v = bias[j];
      #pragma unroll
      for (int kc = 0; kc < 8; ++kc) v += gpart[((long)kc * 4 + b) * 1024 + j];
      outp[i] = v;
    }
    return;
  }
  const int c = blockIdx.x >> 2, b = blockIdx.x & 3;
  long stride = (long)4 * C * T;
  const float* r = p + ((long)b * C + c) * T;
  float* cw = csum + ((long)b * C + c) * T;
  float s = 0, q = 0;
  for (int t = threadIdx.x; t < T; t += 256) {
    float v = r[t];
    for (int k = 1; k < SK; ++k) v += r[t + k * stride];
    if (docopy) cw[t] = v;
    s += v; q += v * v;
  }
  #pragma unroll
  for (int off = 32; off; off >>= 1) { s += __shfl_down(s, off); q += __shfl_down(q, off); }
  __shared__ float rs[4], rq[4];
  int wid = threadIdx.x >> 6, lane = threadIdx.x & 63;
  if (lane == 0) { rs[wid] = s; rq[wid] = q; }
  __syncthreads();
  if (threadIdx.x == 0) {
    sp[c * 4 + b] = rs[0] + rs[1] + rs[2] + rs[3];
    sp[C * 4 + c * 4 + b] = rq[0] + rq[1] + rq[2] + rq[3];
  }
}

// ---------------- final conv: phase-decomposed 3-tap, FUSED bn-apply staging ----------------
__global__ __launch_bounds__(256)
void conv5_kernel(const float* __restrict__ csum_in, const float* __restrict__ sp,
                  const float* __restrict__ g, const float* __restrict__ be,
                  const float* __restrict__ wgt, const float* __restrict__ bias,
                  float* __restrict__ out, int Tout) {
  __shared__ unsigned short sv[64 * 66];
  __shared__ float wph[64 * 13];
  __shared__ float ssc[64], ssh[64];

  const int b = blockIdx.y;
  const int u0 = blockIdx.x * 64;
  const int Tin = Tout >> 2;
  const int tid = threadIdx.x;

  {
    int ci = tid >> 2, pp = tid & 3;
    float s0 = 0, s1 = 0, s2 = 0;
    #pragma unroll
    for (int k = 0; k < 7; ++k) {
      int d = (pp - 3 + k + 4) >> 2;
      float wv = wgt[ci * 7 + k];
      if (d == 0) s0 += wv; else if (d == 1) s1 += wv; else s2 += wv;
    }
    wph[ci * 13 + pp * 3 + 0] = s0;
    wph[ci * 13 + pp * 3 + 1] = s1;
    wph[ci * 13 + pp * 3 + 2] = s2;
  }
  if (tid < 64) {
    float S = sp[tid * 4] + sp[tid * 4 + 1] + sp[tid * 4 + 2] + sp[tid * 4 + 3];
    float Q = sp[256 + tid * 4] + sp[256 + tid * 4 + 1] + sp[256 + tid * 4 + 2] + sp[256 + tid * 4 + 3];
    float n = 4.f * (float)Tin;
    float mean = S / n;
    float var = Q / n - mean * mean;
    float sc = g[tid] * rsqrtf(var + 1e-5f);
    ssc[tid] = sc;
    ssh[tid] = be[tid] - mean * sc;
  }
  __syncthreads();

  const float* inb = csum_in + (long)b * 64 * Tin;
  for (int i = tid; i < 64 * 66; i += 256) {
    int ci = i / 66, uu = i - ci * 66;
    int u = u0 - 1 + uu;
    unsigned short v = 0;
    if (u >= 0 && u < Tin) {
      float t = inb[(long)ci * Tin + u];
      v = f2bf(leaky(t * ssc[ci] + ssh[ci]));
    }
    sv[ci * 66 + uu] = v;
  }
  __syncthreads();

  const int ul = tid >> 2;
  const int chunk = tid & 3;
  float a0 = 0, a1 = 0, a2 = 0, a3 = 0;
  #pragma unroll
  for (int cc = 0; cc < 16; ++cc) {
    int ci = chunk * 16 + cc;
    float v0 = bf2f(sv[ci * 66 + ul]);
    float v1 = bf2f(sv[ci * 66 + ul + 1]);
    float v2 = bf2f(sv[ci * 66 + ul + 2]);
    const float* wp = wph + ci * 13;
    a0 += v0 * wp[0] + v1 * wp[1];
    a1 += v0 * wp[3] + v1 * wp[4] + v2 * wp[5];
    a2 += v0 * wp[6] + v1 * wp[7] + v2 * wp[8];
    a3 += v1 * wp[10] + v2 * wp[11];
  }
  #pragma unroll
  for (int msk = 1; msk <= 2; msk <<= 1) {
    a0 += __shfl_xor(a0, msk);
    a1 += __shfl_xor(a1, msk);
    a2 += __shfl_xor(a2, msk);
    a3 += __shfl_xor(a3, msk);
  }
  if (chunk == 0) {
    float bv = bias[0];
    float4 r = make_float4(a0 + bv, a1 + bv, a2 + bv, a3 + bv);
    *(float4*)(out + (long)b * Tout + (long)(u0 + ul) * 4) = r;
  }
}

extern "C" void kernel_launch(void* const* d_in, const int* in_sizes, int n_in,
                              void* d_out, int out_size, void* d_ws, size_t ws_size,
                              hipStream_t stream) {
  const float* x     = (const float*)d_in[0];
  // d_in[1] = atoms: dead (sparse_code result unused by outputs)
  const float* ew    = (const float*)d_in[2];
  const float* eb    = (const float*)d_in[3];
  const float* w1    = (const float*)d_in[4];
  const float* b1    = (const float*)d_in[5];
  const float* g1    = (const float*)d_in[6];
  const float* be1   = (const float*)d_in[7];
  const float* w2    = (const float*)d_in[8];
  const float* b2    = (const float*)d_in[9];
  const float* g2    = (const float*)d_in[10];
  const float* be2   = (const float*)d_in[11];
  const float* w3    = (const float*)d_in[12];
  const float* b3    = (const float*)d_in[13];
  const float* up_w1 = (const float*)d_in[14];
  const float* up_b1 = (const float*)d_in[15];
  const float* bn_g1 = (const float*)d_in[16];
  const float* bn_b1 = (const float*)d_in[17];
  const float* up_w2 = (const float*)d_in[18];
  const float* up_b2 = (const float*)d_in[19];
  const float* bn_g2 = (const float*)d_in[20];
  const float* bn_b2 = (const float*)d_in[21];
  const float* up_w3 = (const float*)d_in[22];
  const float* up_b3 = (const float*)d_in[23];
  const float* bn_g3 = (const float*)d_in[24];
  const float* bn_b3 = (const float*)d_in[25];
  const float* up_w4 = (const float*)d_in[26];
  const float* up_b4 = (const float*)d_in[27];
  const float* bn_g4 = (const float*)d_in[28];
  const float* bn_b4 = (const float*)d_in[29];
  const float* up_w5 = (const float*)d_in[30];
  const float* up_b5 = (const float*)d_in[31];

  float* out = (float*)d_out;              // [0,131072) = y, [131072,135168) = ctx_out

  float* ws = (float*)d_ws;
  float* part   = ws;                      // 8192
  float* gpart  = part + 8192;             // 32768
  float* t2     = gpart + 32768;           // 4096
  float* statsp = t2 + 4096;               // 4096
  float* csum   = statsp + 4096;           // 2097152
  float* pbuf   = csum + 2097152;          // 4194304
  unsigned short* encbf = (unsigned short*)(pbuf + 4194304);  // 524288 u16
  unsigned short* wbuf  = encbf + 524288;  // 5734400 u16

  // 1: embed (direct-load MFMA, fused ctx partials) + weight packing riders
  embed_pack<<<3744, 256, 0, stream>>>(x, ew, eb, encbf, part,
                                       up_w1, up_w2, up_w3, up_w4, wbuf);

  // 2: conv stage 1 (SK=4, 32-t tiles) + MLP gemm1 rider
  conv1_g<4><<<768, 256, 24320, stream>>>(encbf, wbuf, pbuf,
                                          512, part, w1, gpart, 1);
  // 3: bnsum1 (SK=4) + lnsum1 rider (gpart -> t2)
  bnsum_ln<<<2052, 256, 0, stream>>>(pbuf, statsp, csum, 512, 128, 4, 1, 1,
                                     gpart, b1, g1, be1, t2);
  // 4: conv stage 2 (SK=4, 32-u tiles) + gemm2 rider (t2 -> gpart)
  conv_ph_g<4><<<512, 256, 10880, stream>>>(csum, statsp, bn_g1, bn_b1, wbuf + 3670016,
                                            pbuf, 512, 256, 128,
                                            256, t2, w2, gpart, 0);
  // 5: bnsum2 (SK=4) + lnsum2 rider (gpart -> t2)
  bnsum_ln<<<1028, 256, 0, stream>>>(pbuf, statsp, csum, 256, 512, 4, 1, 1,
                                     gpart, b2, g2, be2, t2);
  // 6: conv stage 3 (SK=2) + gemm3 rider (t2 -> gpart)
  conv_ph_g<2><<<512, 256, 10880, stream>>>(csum, statsp, bn_g2, bn_b2, wbuf + 5242880,
                                            pbuf, 256, 128, 512,
                                            256, t2, w3, gpart, 0);
  // 7: bnsum3 (SK=2) + fin rider (gpart -> ctx_out)
  bnsum_ln<<<528, 256, 0, stream>>>(pbuf, statsp, csum, 128, 2048, 2, 1, 2,
                                    gpart, b3, b3, b3, out + 131072);
  // 8: conv stage 4 (SK=1 -> writes final sums to pbuf directly)
  conv_ph_g<1><<<256, 256, 10880, stream>>>(csum, statsp, bn_g3, bn_b3, wbuf + 5636096,
                                            pbuf, 128, 64, 2048,
                                            256, t2, w3, gpart, -1);
  // 9: bnsum4 (SK=1, stats only - no copy)
  bnsum_ln<<<256, 256, 0, stream>>>(pbuf, statsp, csum, 64, 8192, 1, 0, 0,
                                    gpart, b3, b3, b3, out + 131072);
  // 10: conv stage 5 (reads pbuf directly)
  conv5_kernel<<<dim3(128, 4), 256, 0, stream>>>(pbuf, statsp, bn_g4, bn_b4, up_w5, up_b5, out, 32768);
}